// Round 4
// baseline (259.320 us; speedup 1.0000x reference)
//
#include <hip/hip_runtime.h>

#define IN_F 256
#define OUT_F 64
#define BM 64
#define BK 64
#define LDA 68   // padded leading dims (floats) to break 16-row bank cycles
#define SCAN_B 1024

#define AS_I(f) __builtin_bit_cast(int, f)
#define AS_F(i) __builtin_bit_cast(float, i)
// v += dpp_moved(v); masked/invalid lanes contribute 0 (old=0, bound_ctrl=1)
#define DPP_ADD(v, ctrl, rmask) \
    v += AS_F(__builtin_amdgcn_update_dpp(0, AS_I(v), ctrl, rmask, 0xf, true))

// Full 64-lane sum, broadcast via readlane(63). Pure VALU pipe (DPP).
__device__ __forceinline__ float wave_sum_bcast(float p) {
    DPP_ADD(p, 0x111, 0xf);  // row_shr:1
    DPP_ADD(p, 0x112, 0xf);  // row_shr:2
    DPP_ADD(p, 0x114, 0xf);  // row_shr:4
    DPP_ADD(p, 0x118, 0xf);  // row_shr:8
    DPP_ADD(p, 0x142, 0xa);  // row_bcast:15
    DPP_ADD(p, 0x143, 0xc);  // row_bcast:31
    return AS_F(__builtin_amdgcn_readlane(AS_I(p), 63));
}

#define FMA4(ACC, S, B) \
    ACC.x = fmaf(S, B.x, ACC.x); ACC.y = fmaf(S, B.y, ACC.y); \
    ACC.z = fmaf(S, B.z, ACC.z); ACC.w = fmaf(S, B.w, ACC.w)

// ---------------------------------------------------------------------------
// GEMM hp = h @ w (f32 vector ALU) fused with dst-degree histogram.
// BM=64/BK=64: 782 blocks (~3/CU resident), register double-buffer prefetch
// of the next K-chunk overlaps global latency with the FMA loop.
// ---------------------------------------------------------------------------
__global__ __launch_bounds__(256) void gemm_hist_kernel(const float* __restrict__ h,
                                                        const float* __restrict__ w,
                                                        float* __restrict__ hp, int N,
                                                        const int* __restrict__ dst,
                                                        int* __restrict__ deg, int E) {
    int tid = threadIdx.x;

    // histogram (grid-stride, fire-and-forget atomics)
    for (int e = blockIdx.x * 256 + tid; e < E; e += gridDim.x * 256)
        atomicAdd(&deg[dst[e]], 1);

    __shared__ float As[BM][LDA];
    __shared__ float Bs[BK][LDA];

    int tn   = tid & 15;   // cols tn*4..tn*4+3
    int tm   = tid >> 4;   // rows tm*4..tm*4+3
    int row0 = blockIdx.x * BM;

    // each thread stages 4 float4 of A and 4 float4 of B per K-chunk
    int sf_r  = tid >> 4;          // shared by A (row) and B (k-row)
    int sf_kq = tid & 15;          // float4 index within row
    int gra   = row0 + sf_r; if (gra >= N) gra = N - 1;
    const float* aptr = h + (size_t)gra * IN_F + sf_kq * 4;

    float4 ra[4], rb[4];
#pragma unroll
    for (int it = 0; it < 4; ++it) {
        ra[it] = *(const float4*)(aptr + it * 16 * IN_F * 0 + 0) ; // placeholder, rewritten below
    }
    // prologue: load chunk k0 = 0
#pragma unroll
    for (int it = 0; it < 4; ++it) {
        int f = tid + it * 256;
        int r = f >> 4, kq = f & 15;
        int gr = row0 + r; if (gr >= N) gr = N - 1;
        ra[it] = *(const float4*)(h + (size_t)gr * IN_F + kq * 4);
        rb[it] = *(const float4*)(w + (size_t)r * OUT_F + kq * 4);
    }

    float4 acc[4];
#pragma unroll
    for (int i = 0; i < 4; ++i) acc[i] = make_float4(0.f, 0.f, 0.f, 0.f);

    for (int k0 = 0; k0 < IN_F; k0 += BK) {
        // commit staged registers to LDS
#pragma unroll
        for (int it = 0; it < 4; ++it) {
            int f = tid + it * 256;
            int r = f >> 4, kq = f & 15;
            *(float4*)(&As[r][kq * 4]) = ra[it];
            *(float4*)(&Bs[r][kq * 4]) = rb[it];
        }
        __syncthreads();

        int k1 = k0 + BK;
        if (k1 < IN_F) {   // prefetch next chunk into registers (overlaps compute)
#pragma unroll
            for (int it = 0; it < 4; ++it) {
                int f = tid + it * 256;
                int r = f >> 4, kq = f & 15;
                int gr = row0 + r; if (gr >= N) gr = N - 1;
                ra[it] = *(const float4*)(h + (size_t)gr * IN_F + k1 + kq * 4);
                rb[it] = *(const float4*)(w + (size_t)(k1 + r) * OUT_F + kq * 4);
            }
        }

#pragma unroll 4
        for (int kk = 0; kk < BK; kk += 4) {
            float4 b0 = *(float4*)(&Bs[kk + 0][tn * 4]);
            float4 b1 = *(float4*)(&Bs[kk + 1][tn * 4]);
            float4 b2 = *(float4*)(&Bs[kk + 2][tn * 4]);
            float4 b3 = *(float4*)(&Bs[kk + 3][tn * 4]);
#pragma unroll
            for (int i = 0; i < 4; ++i) {
                float4 a = *(float4*)(&As[tm * 4 + i][kk]);
                FMA4(acc[i], a.x, b0);
                FMA4(acc[i], a.y, b1);
                FMA4(acc[i], a.z, b2);
                FMA4(acc[i], a.w, b3);
            }
        }
        __syncthreads();
    }

#pragma unroll
    for (int i = 0; i < 4; ++i) {
        int gr = row0 + tm * 4 + i;
        if (gr < N) *(float4*)(hp + (size_t)gr * OUT_F + tn * 4) = acc[i];
    }
}

// ---------------------------------------------------------------------------
// Block scan of deg -> local exclusive row_ptr + per-block totals
// ---------------------------------------------------------------------------
__global__ __launch_bounds__(SCAN_B) void scan_blocks(const int* __restrict__ deg,
                                                      int* __restrict__ row_ptr,
                                                      int* __restrict__ partial, int N) {
    __shared__ int wsum[16], woff[16];
    int t    = threadIdx.x;
    int lane = t & 63;
    int wid  = t >> 6;
    int i    = blockIdx.x * SCAN_B + t;
    int v    = (i < N) ? deg[i] : 0;

    int x = v;
#pragma unroll
    for (int off = 1; off < 64; off <<= 1) {
        int y = __shfl_up(x, off, 64);
        if (lane >= off) x += y;
    }
    if (lane == 63) wsum[wid] = x;
    __syncthreads();
    if (t < 16) {
        int s  = wsum[t];
        int xs = s;
#pragma unroll
        for (int off = 1; off < 16; off <<= 1) {
            int y = __shfl_up(xs, off, 64);
            if (t >= off) xs += y;
        }
        woff[t] = xs - s;
    }
    __syncthreads();
    int incl = woff[wid] + x;
    if (i < N) row_ptr[i] = incl - v;
    if (t == SCAN_B - 1) partial[blockIdx.x] = incl;
}

__global__ __launch_bounds__(256) void scan_add(int* __restrict__ row_ptr,
                                                int* __restrict__ cursor,
                                                const int* __restrict__ partial,
                                                int nb, int N, int E) {
    __shared__ int poff[64];
    int t = threadIdx.x;
    if (t < 64) {
        int v = (t < nb) ? partial[t] : 0;
        int x = v;
#pragma unroll
        for (int off = 1; off < 64; off <<= 1) {
            int y = __shfl_up(x, off, 64);
            if (t >= off) x += y;
        }
        poff[t] = x - v;
    }
    __syncthreads();
    int i = blockIdx.x * 256 + t;
    if (i < N) {
        int v = row_ptr[i] + poff[i >> 10];
        row_ptr[i] = v;
        cursor[i]  = v;
    }
    if (i == 0) row_ptr[N] = E;
}

__global__ __launch_bounds__(256) void scatter_kernel(const int* __restrict__ src,
                                                      const int* __restrict__ dst,
                                                      int* __restrict__ cursor,
                                                      int* __restrict__ srcs, int E) {
    int e = blockIdx.x * blockDim.x + threadIdx.x;
    if (e < E) {
        int d   = dst[e];
        int pos = atomicAdd(&cursor[d], 1);
        srcs[pos] = src[e];
    }
}

// ---------------------------------------------------------------------------
// Accumulate: one wave per dst node, lane = feature. 8 independent
// gather + DPP-reduce chains in flight to hide L2/L3 gather latency.
// ---------------------------------------------------------------------------
__global__ __launch_bounds__(256) void accum_kernel(const float* __restrict__ hp,
                                                    const int* __restrict__ row_ptr,
                                                    const int* __restrict__ srcs,
                                                    const float* __restrict__ attw,
                                                    float* __restrict__ out, int N) {
    int v    = (blockIdx.x * blockDim.x + threadIdx.x) >> 6;
    int lane = threadIdx.x & 63;
    if (v >= N) return;

    int beg = row_ptr[v];
    int end = row_ptr[v + 1];
    float hd = hp[(size_t)v * OUT_F + lane];

    float c = 0.f;
#pragma unroll
    for (int i = 0; i < 8; ++i) c += attw[i];

    float acc = 0.f;
    int j = beg;
    for (; j + 8 <= end; j += 8) {
        float a[8];
#pragma unroll
        for (int u = 0; u < 8; ++u) {
            int s = srcs[j + u];                       // wave-uniform -> s_load
            a[u] = hp[(size_t)s * OUT_F + lane];
        }
        float d[8];
#pragma unroll
        for (int u = 0; u < 8; ++u) d[u] = wave_sum_bcast(a[u] * hd);
#pragma unroll
        for (int u = 0; u < 8; ++u) acc = fmaf(d[u], a[u], acc);
    }
    for (; j + 4 <= end; j += 4) {
        float a[4];
#pragma unroll
        for (int u = 0; u < 4; ++u) {
            int s = srcs[j + u];
            a[u] = hp[(size_t)s * OUT_F + lane];
        }
        float d[4];
#pragma unroll
        for (int u = 0; u < 4; ++u) d[u] = wave_sum_bcast(a[u] * hd);
#pragma unroll
        for (int u = 0; u < 4; ++u) acc = fmaf(d[u], a[u], acc);
    }
    for (; j < end; ++j) {
        int s = srcs[j];
        float a = hp[(size_t)s * OUT_F + lane];
        acc = fmaf(wave_sum_bcast(a * hd), a, acc);
    }

    out[(size_t)v * OUT_F + lane] = (end > beg) ? acc * c : hd;
}

extern "C" void kernel_launch(void* const* d_in, const int* in_sizes, int n_in,
                              void* d_out, int out_size, void* d_ws, size_t ws_size,
                              hipStream_t stream) {
    const float* h    = (const float*)d_in[0];
    const float* w    = (const float*)d_in[1];
    const float* attw = (const float*)d_in[2];
    const int*   src  = (const int*)d_in[3];
    const int*   dst  = (const int*)d_in[4];

    int N = in_sizes[0] / IN_F;
    int E = in_sizes[3];

    float* out = (float*)d_out;

    char* p = (char*)d_ws;
    float* hp      = (float*)p;            p += (size_t)N * OUT_F * sizeof(float);
    int*   deg     = (int*)p;              p += ((size_t)N + 4) * sizeof(int);
    int*   row_ptr = (int*)p;              p += ((size_t)N + 4) * sizeof(int);
    int*   cursor  = (int*)p;              p += ((size_t)N + 4) * sizeof(int);
    int*   partial = (int*)p;              p += 64 * sizeof(int);
    int*   srcs    = (int*)p;

    hipMemsetAsync(deg, 0, (size_t)N * sizeof(int), stream);

    gemm_hist_kernel<<<(N + BM - 1) / BM, 256, 0, stream>>>(h, w, hp, N, dst, deg, E);

    int nsb = (N + SCAN_B - 1) / SCAN_B;   // 49 for N=50000 (<= 64 required)
    scan_blocks<<<nsb, SCAN_B, 0, stream>>>(deg, row_ptr, partial, N);
    scan_add<<<(N + 255) / 256, 256, 0, stream>>>(row_ptr, cursor, partial, nsb, N, E);

    scatter_kernel<<<(E + 255) / 256, 256, 0, stream>>>(src, dst, cursor, srcs, E);

    accum_kernel<<<((size_t)N * 64 + 255) / 256, 256, 0, stream>>>(hp, row_ptr, srcs, attw, out, N);
}

// Round 5
// 227.914 us; speedup vs baseline: 1.1378x; 1.1378x over previous
//
#include <hip/hip_runtime.h>

#define IN_F 256
#define OUT_F 64
#define SCAN_B 1024

typedef __attribute__((ext_vector_type(8))) short short8;
typedef __attribute__((ext_vector_type(4))) float f32x4;
typedef unsigned int uint32;
typedef unsigned short ushort16_t;

#define AS_I(f) __builtin_bit_cast(int, f)
#define AS_F(i) __builtin_bit_cast(float, i)
#define DPP_ADD(v, ctrl, rmask) \
    v += AS_F(__builtin_amdgcn_update_dpp(0, AS_I(v), ctrl, rmask, 0xf, true))

// Full 64-lane sum broadcast (pure VALU pipe / DPP).
__device__ __forceinline__ float wave_sum_bcast(float p) {
    DPP_ADD(p, 0x111, 0xf);  // row_shr:1
    DPP_ADD(p, 0x112, 0xf);  // row_shr:2
    DPP_ADD(p, 0x114, 0xf);  // row_shr:4
    DPP_ADD(p, 0x118, 0xf);  // row_shr:8
    DPP_ADD(p, 0x142, 0xa);  // row_bcast:15
    DPP_ADD(p, 0x143, 0xc);  // row_bcast:31
    return AS_F(__builtin_amdgcn_readlane(AS_I(p), 63));
}

__device__ __forceinline__ unsigned short f2bf(float f) {  // RNE f32->bf16
    uint32 u = __builtin_bit_cast(uint32, f);
    u += 0x7fffu + ((u >> 16) & 1u);
    return (unsigned short)(u >> 16);
}
__device__ __forceinline__ float bf2f(unsigned short s) {
    return __builtin_bit_cast(float, (uint32)s << 16);
}

// ---------------------------------------------------------------------------
// hist (256 blocks, capped concurrency to limit deg-line thrash) + wprep:
// blocks 0..7 also build wT2: slot(kb,n) = 16B of bf16 w[kb*8..kb*8+7][n],
// i.e. B-fragment-ready layout for mfma 16x16x32 (k contiguous per n).
// ---------------------------------------------------------------------------
__global__ __launch_bounds__(256) void hist_wprep_kernel(const int* __restrict__ dst,
                                                         int* __restrict__ deg, int E,
                                                         const float* __restrict__ w,
                                                         unsigned short* __restrict__ wt2) {
    int b = blockIdx.x, t = threadIdx.x;
    if (b < 8) {
        int slot = b * 256 + t;            // 2048 slots = 32 kb * 64 n
        int kb = slot >> 6, n = slot & 63;
        unsigned short tmp[8];
#pragma unroll
        for (int j = 0; j < 8; ++j)
            tmp[j] = f2bf(w[(size_t)(kb * 8 + j) * OUT_F + n]);  // lanes: consecutive n -> coalesced
        short8 v;
#pragma unroll
        for (int j = 0; j < 8; ++j) v[j] = (short)tmp[j];
        *(short8*)(wt2 + (size_t)slot * 8) = v;
    }
    for (int e = b * 256 + t; e < E; e += gridDim.x * 256)
        atomicAdd(&deg[dst[e]], 1);
}

// ---------------------------------------------------------------------------
// GEMM hp_bf16 = bf16(h @ w) via MFMA 16x16x32 bf16. NO LDS, NO barriers.
// 256 thr = 4 waves; wave handles 16 rows x 64 cols (4 col-tiles, 8 K-steps).
// A frags straight from global h (f32->bf16 in regs); B frags from wT2 (L2-hot).
// Layouts (m89/m91/m120 verified): A[m=lane&15][k=quad*8+j],
// B[k=quad*8+j][n=lane&15], D row=quad*4+reg col=lane&15.
// ---------------------------------------------------------------------------
__global__ __launch_bounds__(256) void gemm_kernel(const float* __restrict__ h,
                                                   const unsigned short* __restrict__ wt2,
                                                   unsigned short* __restrict__ hpb, int N) {
    int tid  = threadIdx.x;
    int wave = tid >> 6, lane = tid & 63;
    int n16  = lane & 15, quad = lane >> 4;

    int base = blockIdx.x * 64 + wave * 16;
    int arow_i = base + n16; if (arow_i >= N) arow_i = N - 1;
    const float* arow = h + (size_t)arow_i * IN_F;

    f32x4 acc[4];
#pragma unroll
    for (int ct = 0; ct < 4; ++ct) acc[ct] = (f32x4){0.f, 0.f, 0.f, 0.f};

#pragma unroll
    for (int ks = 0; ks < 8; ++ks) {           // K-step of 32
        int k0 = ks * 32;
        float4 a0 = *(const float4*)(arow + k0 + quad * 8);
        float4 a1 = *(const float4*)(arow + k0 + quad * 8 + 4);
        short8 af;
        af[0] = (short)f2bf(a0.x); af[1] = (short)f2bf(a0.y);
        af[2] = (short)f2bf(a0.z); af[3] = (short)f2bf(a0.w);
        af[4] = (short)f2bf(a1.x); af[5] = (short)f2bf(a1.y);
        af[6] = (short)f2bf(a1.z); af[7] = (short)f2bf(a1.w);
        int kb = ks * 4 + quad;                // k-block index for this quad
#pragma unroll
        for (int ct = 0; ct < 4; ++ct) {
            short8 bf = *(const short8*)(wt2 + (size_t)(kb * 64 + ct * 16 + n16) * 8);
            acc[ct] = __builtin_amdgcn_mfma_f32_16x16x32_bf16(af, bf, acc[ct], 0, 0, 0);
        }
    }

#pragma unroll
    for (int ct = 0; ct < 4; ++ct) {
#pragma unroll
        for (int r = 0; r < 4; ++r) {
            int ro = base + quad * 4 + r;
            if (ro < N) hpb[(size_t)ro * OUT_F + ct * 16 + n16] = f2bf(acc[ct][r]);
        }
    }
}

// ---------------------------------------------------------------------------
// Block scan of deg -> local exclusive row_ptr + per-block totals
// ---------------------------------------------------------------------------
__global__ __launch_bounds__(SCAN_B) void scan_blocks(const int* __restrict__ deg,
                                                      int* __restrict__ row_ptr,
                                                      int* __restrict__ partial, int N) {
    __shared__ int wsum[16], woff[16];
    int t = threadIdx.x, lane = t & 63, wid = t >> 6;
    int i = blockIdx.x * SCAN_B + t;
    int v = (i < N) ? deg[i] : 0;

    int x = v;
#pragma unroll
    for (int off = 1; off < 64; off <<= 1) {
        int y = __shfl_up(x, off, 64);
        if (lane >= off) x += y;
    }
    if (lane == 63) wsum[wid] = x;
    __syncthreads();
    if (t < 16) {
        int s = wsum[t], xs = s;
#pragma unroll
        for (int off = 1; off < 16; off <<= 1) {
            int y = __shfl_up(xs, off, 64);
            if (t >= off) xs += y;
        }
        woff[t] = xs - s;
    }
    __syncthreads();
    int incl = woff[wid] + x;
    if (i < N) row_ptr[i] = incl - v;
    if (t == SCAN_B - 1) partial[blockIdx.x] = incl;
}

__global__ __launch_bounds__(256) void scan_add(int* __restrict__ row_ptr,
                                                int* __restrict__ cursor,
                                                const int* __restrict__ partial,
                                                int nb, int N, int E) {
    __shared__ int poff[64];
    int t = threadIdx.x;
    if (t < 64) {
        int v = (t < nb) ? partial[t] : 0;
        int x = v;
#pragma unroll
        for (int off = 1; off < 64; off <<= 1) {
            int y = __shfl_up(x, off, 64);
            if (t >= off) x += y;
        }
        poff[t] = x - v;
    }
    __syncthreads();
    int i = blockIdx.x * 256 + t;
    if (i < N) {
        int v = row_ptr[i] + poff[i >> 10];
        row_ptr[i] = v;
        cursor[i]  = v;
    }
    if (i == 0) row_ptr[N] = E;
}

// 256 blocks: capped concurrency for cursor atomics + scattered stores.
__global__ __launch_bounds__(256) void scatter_kernel(const int* __restrict__ src,
                                                      const int* __restrict__ dst,
                                                      int* __restrict__ cursor,
                                                      int* __restrict__ srcs, int E) {
    for (int e = blockIdx.x * 256 + threadIdx.x; e < E; e += gridDim.x * 256) {
        int d   = dst[e];
        int pos = atomicAdd(&cursor[d], 1);
        srcs[pos] = src[e];
    }
}

// ---------------------------------------------------------------------------
// Accumulate: one wave per dst node, lane = feature. bf16 hp gathers
// (128B/edge), 8 independent gather+DPP chains for latency hiding.
// ---------------------------------------------------------------------------
__global__ __launch_bounds__(256) void accum_kernel(const unsigned short* __restrict__ hpb,
                                                    const int* __restrict__ row_ptr,
                                                    const int* __restrict__ srcs,
                                                    const float* __restrict__ attw,
                                                    float* __restrict__ out, int N) {
    int v    = (blockIdx.x * blockDim.x + threadIdx.x) >> 6;
    int lane = threadIdx.x & 63;
    if (v >= N) return;

    int beg = row_ptr[v];
    int end = row_ptr[v + 1];
    float hd = bf2f(hpb[(size_t)v * OUT_F + lane]);

    float c = 0.f;
#pragma unroll
    for (int i = 0; i < 8; ++i) c += attw[i];

    float acc = 0.f;
    int j = beg;
    for (; j + 8 <= end; j += 8) {
        float a[8];
#pragma unroll
        for (int u = 0; u < 8; ++u) {
            int s = srcs[j + u];
            a[u] = bf2f(hpb[(size_t)s * OUT_F + lane]);
        }
        float d[8];
#pragma unroll
        for (int u = 0; u < 8; ++u) d[u] = wave_sum_bcast(a[u] * hd);
#pragma unroll
        for (int u = 0; u < 8; ++u) acc = fmaf(d[u], a[u], acc);
    }
    for (; j + 4 <= end; j += 4) {
        float a[4];
#pragma unroll
        for (int u = 0; u < 4; ++u) {
            int s = srcs[j + u];
            a[u] = bf2f(hpb[(size_t)s * OUT_F + lane]);
        }
        float d[4];
#pragma unroll
        for (int u = 0; u < 4; ++u) d[u] = wave_sum_bcast(a[u] * hd);
#pragma unroll
        for (int u = 0; u < 4; ++u) acc = fmaf(d[u], a[u], acc);
    }
    for (; j < end; ++j) {
        int s = srcs[j];
        float a = bf2f(hpb[(size_t)s * OUT_F + lane]);
        acc = fmaf(wave_sum_bcast(a * hd), a, acc);
    }

    out[(size_t)v * OUT_F + lane] = (end > beg) ? acc * c : hd;
}

extern "C" void kernel_launch(void* const* d_in, const int* in_sizes, int n_in,
                              void* d_out, int out_size, void* d_ws, size_t ws_size,
                              hipStream_t stream) {
    const float* h    = (const float*)d_in[0];
    const float* w    = (const float*)d_in[1];
    const float* attw = (const float*)d_in[2];
    const int*   src  = (const int*)d_in[3];
    const int*   dst  = (const int*)d_in[4];

    int N = in_sizes[0] / IN_F;
    int E = in_sizes[3];

    float* out = (float*)d_out;

    char* p = (char*)d_ws;
    unsigned short* hpb = (unsigned short*)p;  p += (size_t)N * OUT_F * sizeof(unsigned short);
    unsigned short* wt2 = (unsigned short*)p;  p += (size_t)2048 * 8 * sizeof(unsigned short);
    int* deg     = (int*)p;                    p += ((size_t)N + 4) * sizeof(int);
    int* row_ptr = (int*)p;                    p += ((size_t)N + 4) * sizeof(int);
    int* cursor  = (int*)p;                    p += ((size_t)N + 4) * sizeof(int);
    int* partial = (int*)p;                    p += 64 * sizeof(int);
    int* srcs    = (int*)p;

    hipMemsetAsync(deg, 0, (size_t)N * sizeof(int), stream);

    hist_wprep_kernel<<<256, 256, 0, stream>>>(dst, deg, E, w, wt2);

    gemm_kernel<<<(N + 63) / 64, 256, 0, stream>>>(h, wt2, hpb, N);

    int nsb = (N + SCAN_B - 1) / SCAN_B;   // 49 for N=50000 (<= 64 required)
    scan_blocks<<<nsb, SCAN_B, 0, stream>>>(deg, row_ptr, partial, N);
    scan_add<<<(N + 255) / 256, 256, 0, stream>>>(row_ptr, cursor, partial, nsb, N, E);

    scatter_kernel<<<256, 256, 0, stream>>>(src, dst, cursor, srcs, E);

    accum_kernel<<<((size_t)N * 64 + 255) / 256, 256, 0, stream>>>(hpb, row_ptr, srcs, attw, out, N);
}